// Round 3
// baseline (550.825 us; speedup 1.0000x reference)
//
#include <hip/hip_runtime.h>

#define N_NODES 50000
#define N_EDGES 1600000
#define F 32
#define SCAN_THREADS 1024
#define CHUNK ((N_NODES + SCAN_THREADS - 1) / SCAN_THREADS)   // 49

// ---------- CSR build (segment by dst; shared by stage 1 and stage 3) ----------

__global__ void k_hist(const int* __restrict__ dst, int* __restrict__ deg) {
    int e = blockIdx.x * blockDim.x + threadIdx.x;
    if (e < N_EDGES) atomicAdd(&deg[dst[e]], 1);
}

__global__ __launch_bounds__(SCAN_THREADS)
void k_scan(const int* __restrict__ deg,
            int* __restrict__ row_off,
            int* __restrict__ fill_pos) {
    __shared__ int s[SCAN_THREADS];
    int t = threadIdx.x;
    int start = t * CHUNK;
    int end = min(start + CHUNK, N_NODES);

    int sum = 0;
    for (int i = start; i < end; ++i) sum += deg[i];
    s[t] = sum;
    __syncthreads();
    // Hillis-Steele inclusive scan over 1024 partials.
    for (int off = 1; off < SCAN_THREADS; off <<= 1) {
        int v = (t >= off) ? s[t - off] : 0;
        __syncthreads();
        s[t] += v;
        __syncthreads();
    }
    int run = (t == 0) ? 0 : s[t - 1];
    for (int i = start; i < end; ++i) {
        row_off[i] = run;
        fill_pos[i] = run;
        run += deg[i];
    }
    if (start < N_NODES && end == N_NODES) row_off[N_NODES] = run;
}

__global__ void k_fill(const int* __restrict__ dst,
                       int* __restrict__ fill_pos,
                       int* __restrict__ eid) {
    int e = blockIdx.x * blockDim.x + threadIdx.x;
    if (e < N_EDGES) {
        int p = atomicAdd(&fill_pos[dst[e]], 1);
        eid[p] = e;
    }
}

// ---------- Stage 1+2 fused: node_mean[n] = mean of inputs over in-edges ----------
// One wave per node. lane = eslot*8 + q: 8 edges/iter, each edge read as
// 8 lanes x float4 = 128B contiguous. xor-shuffle reduce over edge slots.
__global__ void k_node_mean(const float* __restrict__ inputs,
                            const int* __restrict__ eid,
                            const int* __restrict__ row_off,
                            float* __restrict__ node_mean) {
    int wave = (blockIdx.x * blockDim.x + threadIdx.x) >> 6;
    if (wave >= N_NODES) return;
    int lane  = threadIdx.x & 63;
    int eslot = lane >> 3;       // 0..7
    int q     = lane & 7;        // float4 quad -> features q*4..q*4+3

    int s0 = row_off[wave];
    int s1 = row_off[wave + 1];

    float4 acc = {0.f, 0.f, 0.f, 0.f};
    for (int i = s0 + eslot; i < s1; i += 8) {
        int e = eid[i];
        float4 v = *reinterpret_cast<const float4*>(&inputs[(size_t)e * F + q * 4]);
        acc.x += v.x; acc.y += v.y; acc.z += v.z; acc.w += v.w;
    }
    #pragma unroll
    for (int m = 8; m <= 32; m <<= 1) {
        acc.x += __shfl_xor(acc.x, m);
        acc.y += __shfl_xor(acc.y, m);
        acc.z += __shfl_xor(acc.z, m);
        acc.w += __shfl_xor(acc.w, m);
    }
    if (eslot == 0) {
        float r = 1.0f / fmaxf((float)(s1 - s0), 1.0f);
        float4 o = {acc.x * r, acc.y * r, acc.z * r, acc.w * r};
        *reinterpret_cast<float4*>(&node_mean[(size_t)wave * F + q * 4]) = o;
    }
}

// ---------- Stage 3: node_h[n] = sum over in-edges of node_mean[src[e]] ----------
__global__ void k_node_h(const int* __restrict__ src,
                         const int* __restrict__ eid,
                         const int* __restrict__ row_off,
                         const float* __restrict__ node_mean,
                         float* __restrict__ node_h) {
    int wave = (blockIdx.x * blockDim.x + threadIdx.x) >> 6;
    if (wave >= N_NODES) return;
    int lane  = threadIdx.x & 63;
    int eslot = lane >> 3;
    int q     = lane & 7;

    int s0 = row_off[wave];
    int s1 = row_off[wave + 1];

    float4 acc = {0.f, 0.f, 0.f, 0.f};
    for (int i = s0 + eslot; i < s1; i += 8) {
        int s = src[eid[i]];
        float4 v = *reinterpret_cast<const float4*>(&node_mean[(size_t)s * F + q * 4]);
        acc.x += v.x; acc.y += v.y; acc.z += v.z; acc.w += v.w;
    }
    #pragma unroll
    for (int m = 8; m <= 32; m <<= 1) {
        acc.x += __shfl_xor(acc.x, m);
        acc.y += __shfl_xor(acc.y, m);
        acc.z += __shfl_xor(acc.z, m);
        acc.w += __shfl_xor(acc.w, m);
    }
    if (eslot == 0) {
        *reinterpret_cast<float4*>(&node_h[(size_t)wave * F + q * 4]) = acc;
    }
}

// ---------- Stage 3.5: node_p = node_h @ W^T ----------
__global__ void k_project(const float* __restrict__ node_h,
                          const float* __restrict__ W,
                          float* __restrict__ node_p) {
    __shared__ float Wl[32][33];
    __shared__ float hr[8][32];

    int tid = threadIdx.x;
    #pragma unroll
    for (int i = tid; i < 1024; i += 256) {
        Wl[i >> 5][i & 31] = W[i];
    }

    int ln = tid >> 5;
    int o  = tid & 31;
    int n  = blockIdx.x * 8 + ln;

    float v = 0.0f;
    if (n < N_NODES) v = node_h[(size_t)n * F + o];
    hr[ln][o] = v;
    __syncthreads();

    if (n < N_NODES) {
        float acc = 0.0f;
        #pragma unroll
        for (int i = 0; i < 32; ++i) {
            acc += hr[ln][i] * Wl[o][i];
        }
        node_p[(size_t)n * F + o] = acc;
    }
}

// ---------- Stage 4: out[e] = 0.5*(node_p[src] + node_p[dst]) + b ----------
__global__ void k_edge_out(const int* __restrict__ src,
                           const int* __restrict__ dst,
                           const float* __restrict__ node_p,
                           const float* __restrict__ b,
                           float* __restrict__ out) {
    int tid = blockIdx.x * blockDim.x + threadIdx.x;   // e*8 + q
    if (tid >= N_EDGES * 8) return;
    int e = tid >> 3;
    int q = tid & 7;
    int s = src[e];
    int d = dst[e];

    const float4 a  = *reinterpret_cast<const float4*>(&node_p[(size_t)s * F + q * 4]);
    const float4 c  = *reinterpret_cast<const float4*>(&node_p[(size_t)d * F + q * 4]);
    const float4 bb = *reinterpret_cast<const float4*>(&b[q * 4]);

    float4 r;
    r.x = 0.5f * (a.x + c.x) + bb.x;
    r.y = 0.5f * (a.y + c.y) + bb.y;
    r.z = 0.5f * (a.z + c.z) + bb.z;
    r.w = 0.5f * (a.w + c.w) + bb.w;

    *reinterpret_cast<float4*>(&out[(size_t)e * F + q * 4]) = r;
}

extern "C" void kernel_launch(void* const* d_in, const int* in_sizes, int n_in,
                              void* d_out, int out_size, void* d_ws, size_t ws_size,
                              hipStream_t stream) {
    const float* inputs = (const float*)d_in[0];
    const int*   src    = (const int*)d_in[1];
    const int*   dst    = (const int*)d_in[2];
    const float* W      = (const float*)d_in[3];
    const float* b      = (const float*)d_in[4];
    float* out = (float*)d_out;

    // Workspace layout
    int* deg      = (int*)d_ws;                    // N
    int* row_off  = deg + N_NODES;                 // N+1
    int* fill_pos = row_off + N_NODES + 1;         // N
    int* eid      = fill_pos + N_NODES;            // E
    float* node_mean = (float*)(eid + N_EDGES);    // N*F  (reused as node_p)
    float* node_h    = node_mean + (size_t)N_NODES * F;  // N*F
    float* node_p    = node_mean;                  // alias: node_mean dead after k_node_h

    // Only the histogram needs zeroing.
    hipMemsetAsync(deg, 0, N_NODES * sizeof(int), stream);

    k_hist<<<(N_EDGES + 255) / 256, 256, 0, stream>>>(dst, deg);
    k_scan<<<1, SCAN_THREADS, 0, stream>>>(deg, row_off, fill_pos);
    k_fill<<<(N_EDGES + 255) / 256, 256, 0, stream>>>(dst, fill_pos, eid);

    // 1 wave per node, 4 waves per block.
    int node_blocks = (N_NODES + 3) / 4;
    k_node_mean<<<node_blocks, 256, 0, stream>>>(inputs, eid, row_off, node_mean);
    k_node_h<<<node_blocks, 256, 0, stream>>>(src, eid, row_off, node_mean, node_h);

    k_project<<<(N_NODES + 7) / 8, 256, 0, stream>>>(node_h, W, node_p);
    k_edge_out<<<(N_EDGES * 8 + 255) / 256, 256, 0, stream>>>(src, dst, node_p, b, out);
}